// Round 7
// baseline (120.198 us; speedup 1.0000x reference)
//
#include <hip/hip_runtime.h>
#include <math.h>

#define N_NODES 10000
#define N_EDGES 640000
#define NB      100                 // hist/scatter blocks
#define CH      (N_EDGES / NB)      // 6400 edges per block
#define HP      10016               // histogram pitch (padded)
#define NPM     (N_NODES / NB)      // 100 nodes per block in mid phase
#define GB      313                 // gemm blocks per matrix ((10000+31)/32)

typedef unsigned short ushort4_t __attribute__((ext_vector_type(4)));
typedef unsigned short ushort8_t __attribute__((ext_vector_type(8)));

__device__ inline unsigned short f2bf(float f) {
    unsigned int u = __float_as_uint(f);
    u = (u + 0x7FFFu + ((u >> 16) & 1u)) >> 16;   // RNE
    return (unsigned short)u;
}
__device__ inline float bf2f(unsigned short s) {
    return __uint_as_float(((unsigned int)s) << 16);
}

// ---- device-scope grid barrier ----
__device__ __forceinline__ void gbar(int* bar, int slot, int nblk) {
    __syncthreads();
    if (threadIdx.x == 0) {
        int* cnt = bar + slot;
        int* gen = bar + 8 + slot;
        int g = atomicAdd(gen, 0);
        __threadfence();
        if (atomicAdd(cnt, 1) == nblk - 1) {
            __threadfence();
            atomicAdd(gen, 1);
        } else {
            while (atomicAdd(gen, 0) == g) __builtin_amdgcn_s_sleep(4);
        }
        __threadfence();
    }
    __syncthreads();
}

// ---- fused: blocks [0,NB) = LDS histogram;  blocks [NB, NB+2*GB) = dual GEMM ----
// hist: h[b][*] = counts of dst in chunk b.  gemm: T1 = x@W1 (bf16), orig = x@Wdown+bdown.
__global__ __launch_bounds__(256) void k_hist_gemm2(const int* __restrict__ dst,
                                                    int* __restrict__ hmat,
                                                    int* __restrict__ bar,
                                                    const float* __restrict__ X,
                                                    const float* __restrict__ W1,
                                                    const float* __restrict__ Wdown,
                                                    const float* __restrict__ bdown,
                                                    unsigned short* __restrict__ outT,
                                                    float* __restrict__ outB, int n) {
    __shared__ char smem[81920];     // union: hist 40KB | gemm xs 16KB + ws 64KB
    int t = threadIdx.x;

    if (blockIdx.x < NB) {
        // ---------------- histogram branch ----------------
        int* hs = (int*)smem;
        if (blockIdx.x == 0 && t < 16) bar[t] = 0;   // zero barrier for next kernel
        for (int j = t; j < HP; j += 256) hs[j] = 0;
        __syncthreads();
        int base = blockIdx.x * CH;
#pragma unroll 4
        for (int j = t; j < CH; j += 256) atomicAdd(&hs[dst[base + j]], 1);
        __syncthreads();
        int* out = hmat + blockIdx.x * HP;
        for (int j = t; j < N_NODES; j += 256) out[j] = hs[j];
        return;
    }

    // ---------------- GEMM branch ----------------
    float* xs = (float*)smem;                 // 32*128 f32
    float* wsm = (float*)(smem + 16384);      // 128*128 f32
    int bid = blockIdx.x - NB;
    int which = (bid >= GB) ? 1 : 0;
    int bx = which ? bid - GB : bid;
    int tile0 = bx * 32;
    const float* W = which ? Wdown : W1;

    const float4* Wv = (const float4*)W;
    float4* wsv = (float4*)wsm;
#pragma unroll
    for (int q = 0; q < 16; ++q) wsv[t + 256 * q] = Wv[t + 256 * q];

    const float4* Xv = (const float4*)X;
    float4* xsv = (float4*)xs;
#pragma unroll
    for (int q = 0; q < 4; ++q) {
        int idx = t + 256 * q;
        int row = tile0 + (idx >> 5);
        float4 v = make_float4(0.f, 0.f, 0.f, 0.f);
        if (row < n) v = Xv[(size_t)row * 32 + (idx & 31)];
        xsv[idx] = v;
    }
    __syncthreads();

    int c4 = t & 31;
    int rg = t >> 5;
    float4 acc[4];
#pragma unroll
    for (int p = 0; p < 4; ++p) acc[p] = make_float4(0.f, 0.f, 0.f, 0.f);

    const float4* wsr = (const float4*)wsm;
    const float4* xsr = (const float4*)xs;
#pragma unroll 4
    for (int kq = 0; kq < 32; ++kq) {
        float4 w0 = wsr[(4 * kq + 0) * 32 + c4];
        float4 w1 = wsr[(4 * kq + 1) * 32 + c4];
        float4 w2 = wsr[(4 * kq + 2) * 32 + c4];
        float4 w3 = wsr[(4 * kq + 3) * 32 + c4];
#pragma unroll
        for (int p = 0; p < 4; ++p) {
            float4 xv = xsr[(rg * 4 + p) * 32 + kq];
            acc[p].x += xv.x * w0.x + xv.y * w1.x + xv.z * w2.x + xv.w * w3.x;
            acc[p].y += xv.x * w0.y + xv.y * w1.y + xv.z * w2.y + xv.w * w3.y;
            acc[p].z += xv.x * w0.z + xv.y * w1.z + xv.z * w2.z + xv.w * w3.z;
            acc[p].w += xv.x * w0.w + xv.y * w1.w + xv.z * w2.w + xv.w * w3.w;
        }
    }
    if (which == 0) {
#pragma unroll
        for (int p = 0; p < 4; ++p) {
            int row = tile0 + rg * 4 + p;
            if (row < n) {
                ushort4_t o;
                o[0] = f2bf(acc[p].x); o[1] = f2bf(acc[p].y);
                o[2] = f2bf(acc[p].z); o[3] = f2bf(acc[p].w);
                ((ushort4_t*)outT)[(size_t)row * 32 + c4] = o;
            }
        }
    } else {
        float4 bv = ((const float4*)bdown)[c4];
#pragma unroll
        for (int p = 0; p < 4; ++p) {
            int row = tile0 + rg * 4 + p;
            if (row < n) {
                float4 o;
                o.x = acc[p].x + bv.x; o.y = acc[p].y + bv.y;
                o.z = acc[p].z + bv.z; o.w = acc[p].w + bv.w;
                ((float4*)outB)[(size_t)row * 32 + c4] = o;
            }
        }
    }
}

// ---- fused mid (colsum/scan/base) + scatter, 100 blocks, 2 grid barriers ----
__global__ __launch_bounds__(256) void k_midsc(const int* __restrict__ src,
                                               const int* __restrict__ dst,
                                               const int* __restrict__ h,
                                               int* bar,
                                               int* __restrict__ rangesum,
                                               int* __restrict__ offsets,
                                               float* __restrict__ dis,
                                               int* __restrict__ bmat,
                                               int* __restrict__ csr) {
    __shared__ int cur[N_NODES];   // scatter cursors (40KB)
    __shared__ int ldeg[128];
    __shared__ int lofs[128];
    __shared__ int rsl[NB];
    __shared__ int sP;
    int b = blockIdx.x, t = threadIdx.x;
    int i = b * NPM + t;
    bool act = (t < NPM);

    // phase 1: deg (column sum over NB hists), dis, local scan
    int s = 0;
    if (act) {
#pragma unroll 5
        for (int bb = 0; bb < NB; ++bb) s += h[bb * HP + i];
        dis[i] = rsqrtf((float)(s + 1));   // +1 self-loop
        ldeg[t] = s;
    }
    __syncthreads();
    if (t == 0) {
        int run = 0;
        for (int j = 0; j < NPM; ++j) { lofs[j] = run; run += ldeg[j]; }
        rangesum[b] = run;
    }
    gbar(bar, 0, NB);

    // phase 2: global prefix + offsets + per-(block,node) bases
    if (t < NB) rsl[t] = rangesum[t];
    __syncthreads();
    if (t == 0) {
        int P = 0;
        for (int bb = 0; bb < b; ++bb) P += rsl[bb];
        sP = P;
        if (b == NB - 1) offsets[N_NODES] = P + rsl[b];
    }
    __syncthreads();
    if (act) {
        int run = sP + lofs[t];
        offsets[i] = run;
#pragma unroll 5
        for (int bb = 0; bb < NB; ++bb) {
            bmat[bb * HP + i] = run;
            run += h[bb * HP + i];
        }
    }
    gbar(bar, 1, NB);

    // phase 3: scatter via private LDS cursors
    const int* mybase = bmat + b * HP;
    for (int j = t; j < N_NODES; j += 256) cur[j] = mybase[j];
    __syncthreads();
    int off = b * CH;
#pragma unroll 4
    for (int j = t; j < CH; j += 256) {
        int d = dst[off + j];
        int sv = src[off + j];
        int p = atomicAdd(&cur[d], 1);
        csr[p] = sv;
    }
}

// ---- single GEMM (T2 = h1 @ W2, bf16 out) ----
__global__ __launch_bounds__(256) void k_gemm(const float* __restrict__ X,
                                              const float* __restrict__ W,
                                              unsigned short* __restrict__ Y, int n) {
    __shared__ float xs[32 * 128];
    __shared__ float ws[128 * 128];
    int t = threadIdx.x;
    int tile0 = blockIdx.x * 32;

    const float4* Wv = (const float4*)W;
    float4* wsv = (float4*)ws;
#pragma unroll
    for (int q = 0; q < 16; ++q) wsv[t + 256 * q] = Wv[t + 256 * q];

    const float4* Xv = (const float4*)X;
    float4* xsv = (float4*)xs;
#pragma unroll
    for (int q = 0; q < 4; ++q) {
        int idx = t + 256 * q;
        int row = tile0 + (idx >> 5);
        float4 v = make_float4(0.f, 0.f, 0.f, 0.f);
        if (row < n) v = Xv[(size_t)row * 32 + (idx & 31)];
        xsv[idx] = v;
    }
    __syncthreads();

    int c4 = t & 31;
    int rg = t >> 5;
    float4 acc[4];
#pragma unroll
    for (int p = 0; p < 4; ++p) acc[p] = make_float4(0.f, 0.f, 0.f, 0.f);

    const float4* wsr = (const float4*)ws;
    const float4* xsr = (const float4*)xs;
#pragma unroll 4
    for (int kq = 0; kq < 32; ++kq) {
        float4 w0 = wsr[(4 * kq + 0) * 32 + c4];
        float4 w1 = wsr[(4 * kq + 1) * 32 + c4];
        float4 w2 = wsr[(4 * kq + 2) * 32 + c4];
        float4 w3 = wsr[(4 * kq + 3) * 32 + c4];
#pragma unroll
        for (int p = 0; p < 4; ++p) {
            float4 xv = xsr[(rg * 4 + p) * 32 + kq];
            acc[p].x += xv.x * w0.x + xv.y * w1.x + xv.z * w2.x + xv.w * w3.x;
            acc[p].y += xv.x * w0.y + xv.y * w1.y + xv.z * w2.y + xv.w * w3.y;
            acc[p].z += xv.x * w0.z + xv.y * w1.z + xv.z * w2.z + xv.w * w3.z;
            acc[p].w += xv.x * w0.w + xv.y * w1.w + xv.z * w2.w + xv.w * w3.w;
        }
    }
#pragma unroll
    for (int p = 0; p < 4; ++p) {
        int row = tile0 + rg * 4 + p;
        if (row < n) {
            ushort4_t o;
            o[0] = f2bf(acc[p].x); o[1] = f2bf(acc[p].y);
            o[2] = f2bf(acc[p].z); o[3] = f2bf(acc[p].w);
            ((ushort4_t*)Y)[(size_t)row * 32 + c4] = o;
        }
    }
}

// ---- layer-1 aggregation: h1 = relu(agg(T1)+b1) -> f32 ----
__global__ __launch_bounds__(256) void k_agg1(const unsigned short* __restrict__ T,
                                              const float* __restrict__ dis,
                                              const int* __restrict__ offsets,
                                              const int* __restrict__ csr,
                                              const float* __restrict__ bias,
                                              float* __restrict__ Y, int n) {
    __shared__ float red[3][16][9];
    int i = blockIdx.x;
    int t = threadIdx.x;
    int c8 = t & 15;
    int es = t >> 4;
    int wave = t >> 6;
    int lane = t & 63;

    int e0 = offsets[i], e1 = offsets[i + 1];
    const ushort8_t* T8 = (const ushort8_t*)T;

    float acc[8];
#pragma unroll
    for (int j = 0; j < 8; ++j) acc[j] = 0.f;

    int e = e0 + es;
    for (; e + 16 < e1; e += 32) {
        int s0 = csr[e];
        int s1 = csr[e + 16];
        float w0 = dis[s0];
        float w1 = dis[s1];
        ushort8_t v0 = T8[(size_t)s0 * 16 + c8];
        ushort8_t v1 = T8[(size_t)s1 * 16 + c8];
#pragma unroll
        for (int j = 0; j < 8; ++j)
            acc[j] += w0 * bf2f(v0[j]) + w1 * bf2f(v1[j]);
    }
    if (e < e1) {
        int s0 = csr[e];
        float w0 = dis[s0];
        ushort8_t v0 = T8[(size_t)s0 * 16 + c8];
#pragma unroll
        for (int j = 0; j < 8; ++j) acc[j] += w0 * bf2f(v0[j]);
    }

#pragma unroll
    for (int j = 0; j < 8; ++j) {
        acc[j] += __shfl_xor(acc[j], 16, 64);
        acc[j] += __shfl_xor(acc[j], 32, 64);
    }
    if (wave > 0 && lane < 16) {
#pragma unroll
        for (int j = 0; j < 8; ++j) red[wave - 1][lane][j] = acc[j];
    }
    __syncthreads();
    if (wave == 0 && lane < 16) {
#pragma unroll
        for (int j = 0; j < 8; ++j)
            acc[j] += red[0][lane][j] + red[1][lane][j] + red[2][lane][j];

        float di = dis[i];
        ushort8_t sv = T8[(size_t)i * 16 + c8];
#pragma unroll
        for (int j = 0; j < 8; ++j) acc[j] += di * bf2f(sv[j]);
#pragma unroll
        for (int j = 0; j < 8; ++j)
            acc[j] = fmaxf(di * acc[j] + bias[c8 * 8 + j], 0.f);

        float4* Y4 = (float4*)Y;
        Y4[(size_t)i * 32 + c8 * 2]     = make_float4(acc[0], acc[1], acc[2], acc[3]);
        Y4[(size_t)i * 32 + c8 * 2 + 1] = make_float4(acc[4], acc[5], acc[6], acc[7]);
    }
}

// ---- layer-2 aggregation fused with all three heads ----
__global__ __launch_bounds__(256) void k_agg2h(const unsigned short* __restrict__ T,
                                               const float* __restrict__ dis,
                                               const int* __restrict__ offsets,
                                               const int* __restrict__ csr,
                                               const float* __restrict__ bias,
                                               const float* __restrict__ resid,
                                               const float* __restrict__ Wlin,
                                               const float* __restrict__ blin,
                                               const float* __restrict__ Wd2,
                                               const float* __restrict__ bd2,
                                               const float* __restrict__ Wd3,
                                               const float* __restrict__ bd3,
                                               float* __restrict__ out1,
                                               float* __restrict__ out2,
                                               float* __restrict__ out3, int n) {
    __shared__ float red[3][16][9];
    __shared__ float hrow[128];
    int i = blockIdx.x;
    int t = threadIdx.x;
    int c8 = t & 15;
    int es = t >> 4;
    int wave = t >> 6;
    int lane = t & 63;

    int e0 = offsets[i], e1 = offsets[i + 1];
    const ushort8_t* T8 = (const ushort8_t*)T;

    float acc[8];
#pragma unroll
    for (int j = 0; j < 8; ++j) acc[j] = 0.f;

    int e = e0 + es;
    for (; e + 16 < e1; e += 32) {
        int s0 = csr[e];
        int s1 = csr[e + 16];
        float w0 = dis[s0];
        float w1 = dis[s1];
        ushort8_t v0 = T8[(size_t)s0 * 16 + c8];
        ushort8_t v1 = T8[(size_t)s1 * 16 + c8];
#pragma unroll
        for (int j = 0; j < 8; ++j)
            acc[j] += w0 * bf2f(v0[j]) + w1 * bf2f(v1[j]);
    }
    if (e < e1) {
        int s0 = csr[e];
        float w0 = dis[s0];
        ushort8_t v0 = T8[(size_t)s0 * 16 + c8];
#pragma unroll
        for (int j = 0; j < 8; ++j) acc[j] += w0 * bf2f(v0[j]);
    }

#pragma unroll
    for (int j = 0; j < 8; ++j) {
        acc[j] += __shfl_xor(acc[j], 16, 64);
        acc[j] += __shfl_xor(acc[j], 32, 64);
    }
    if (wave > 0 && lane < 16) {
#pragma unroll
        for (int j = 0; j < 8; ++j) red[wave - 1][lane][j] = acc[j];
    }
    __syncthreads();
    if (wave == 0 && lane < 16) {
#pragma unroll
        for (int j = 0; j < 8; ++j)
            acc[j] += red[0][lane][j] + red[1][lane][j] + red[2][lane][j];

        float di = dis[i];
        ushort8_t sv = T8[(size_t)i * 16 + c8];
#pragma unroll
        for (int j = 0; j < 8; ++j) acc[j] += di * bf2f(sv[j]);

        const float4* rv4 = (const float4*)resid;
        float4 r0 = rv4[(size_t)i * 32 + c8 * 2];
        float4 r1 = rv4[(size_t)i * 32 + c8 * 2 + 1];
#pragma unroll
        for (int j = 0; j < 8; ++j) acc[j] = di * acc[j] + bias[c8 * 8 + j];
        acc[0] += r0.x; acc[1] += r0.y; acc[2] += r0.z; acc[3] += r0.w;
        acc[4] += r1.x; acc[5] += r1.y; acc[6] += r1.z; acc[7] += r1.w;

#pragma unroll
        for (int j = 0; j < 8; ++j) hrow[c8 * 8 + j] = acc[j];
    }
    __syncthreads();

    if (wave == 0) {
        float h0 = hrow[lane];
        float h1 = hrow[64 + lane];
        float p2 = h0 * Wd2[lane] + h1 * Wd2[64 + lane];
        float p3 = h0 * Wd3[lane] + h1 * Wd3[64 + lane];
#pragma unroll
        for (int d = 1; d < 64; d <<= 1) {
            p2 += __shfl_xor(p2, d, 64);
            p3 += __shfl_xor(p3, d, 64);
        }
        if (lane == 0) {
            out2[i] = p2 + bd2[0];
            out3[i] = p3 + bd3[0];
        }
        int c = lane & 15, kg = lane >> 4;
        float z = 0.f;
#pragma unroll 8
        for (int j = 0; j < 32; ++j) {
            int k = kg * 32 + j;
            z += hrow[k] * Wlin[k * 16 + c];
        }
        z += __shfl_xor(z, 16, 64);
        z += __shfl_xor(z, 32, 64);
        z += blin[c];
        float m = z;
#pragma unroll
        for (int d = 1; d < 16; d <<= 1) m = fmaxf(m, __shfl_xor(m, d, 64));
        float ex = expf(z - m);
        float ssum = ex;
#pragma unroll
        for (int d = 1; d < 16; d <<= 1) ssum += __shfl_xor(ssum, d, 64);
        float lsm = z - m - logf(ssum);
        if (lane < 16) out1[(size_t)i * 16 + c] = lsm;
    }
}

extern "C" void kernel_launch(void* const* d_in, const int* in_sizes, int n_in,
                              void* d_out, int out_size, void* d_ws, size_t ws_size,
                              hipStream_t stream) {
    const float* x     = (const float*)d_in[0];
    const int*   ei    = (const int*)d_in[1];
    const float* W1    = (const float*)d_in[2];
    const float* b1    = (const float*)d_in[3];
    const float* W2    = (const float*)d_in[4];
    const float* b2    = (const float*)d_in[5];
    const float* Wlin1 = (const float*)d_in[6];
    const float* blin1 = (const float*)d_in[7];
    const float* Wdeg2 = (const float*)d_in[8];
    const float* bdeg2 = (const float*)d_in[9];
    const float* Wdeg3 = (const float*)d_in[10];
    const float* bdeg3 = (const float*)d_in[11];
    const float* Wdown = (const float*)d_in[12];
    const float* bdown = (const float*)d_in[13];

    const int n = N_NODES, E = N_EDGES;
    const int* src = ei;
    const int* dst = ei + E;

    char* ws = (char*)d_ws;
    int*            bar      = (int*)ws;                          // 64
    int*            hmat     = bar + 64;                          // NB*HP
    int*            bmat     = hmat + NB * HP;                    // NB*HP
    int*            rangesum = bmat + NB * HP;                    // 128
    int*            offsets  = rangesum + 128;                    // 10048
    float*          dis      = (float*)(offsets + 10048);         // 10016
    int*            csr      = (int*)(dis + HP);                  // 640000
    unsigned short* bufT     = (unsigned short*)(csr + E);        // bf16 n*128
    float*          bufB     = (float*)(bufT + (size_t)n * 128);  // f32 n*128
    float*          bufC     = bufB + (size_t)n * 128;            // f32 n*128

    // 1: histogram (100 blocks) || dual GEMM (626 blocks) -- independent
    k_hist_gemm2<<<NB + 2 * GB, 256, 0, stream>>>(dst, hmat, bar, x, W1, Wdown,
                                                  bdown, bufT, bufB, n);
    // 2: colsum/scan/base + CSR scatter (cooperative, 100 blocks)
    k_midsc<<<NB, 256, 0, stream>>>(src, dst, hmat, bar, rangesum, offsets,
                                    dis, bmat, csr);
    // 3: h1 = relu(agg(T1) + b1)
    k_agg1<<<n, 256, 0, stream>>>(bufT, dis, offsets, csr, b1, bufC, n);
    // 4: T2 = h1 @ W2
    k_gemm<<<(n + 31) / 32, 256, 0, stream>>>(bufC, W2, bufT, n);
    // 5: h2 = agg(T2) + b2 + orig, fused heads
    float* out1 = (float*)d_out;
    float* out2 = out1 + (size_t)n * 16;
    float* out3 = out2 + n;
    k_agg2h<<<n, 256, 0, stream>>>(bufT, dis, offsets, csr, b2, bufB,
                                   Wlin1, blin1, Wdeg2, bdeg2, Wdeg3, bdeg3,
                                   out1, out2, out3, n);
}

// Round 8
// 105.024 us; speedup vs baseline: 1.1445x; 1.1445x over previous
//
#include <hip/hip_runtime.h>
#include <math.h>

#define N_NODES 10000
#define N_EDGES 640000
#define NB      100                 // hist chunks
#define CH      (N_EDGES / NB)      // 6400 edges per chunk
#define HP      10016               // histogram pitch (padded)
#define GB      313                 // gemm blocks per matrix
#define NBLK    40                  // k_mid blocks (co-resident)
#define NPB2    250                 // nodes per k_mid block

typedef unsigned short ushort4_t __attribute__((ext_vector_type(4)));
typedef unsigned short ushort8_t __attribute__((ext_vector_type(8)));

__device__ inline unsigned short f2bf(float f) {
    unsigned int u = __float_as_uint(f);
    u = (u + 0x7FFFu + ((u >> 16) & 1u)) >> 16;   // RNE
    return (unsigned short)u;
}
__device__ inline float bf2f(unsigned short s) {
    return __uint_as_float(((unsigned int)s) << 16);
}

// ---- device-scope grid barrier ----
__device__ __forceinline__ void gbar(int* bar, int slot, int nblk) {
    __syncthreads();
    if (threadIdx.x == 0) {
        int* cnt = bar + slot;
        int* gen = bar + 8 + slot;
        int g = atomicAdd(gen, 0);
        __threadfence();
        if (atomicAdd(cnt, 1) == nblk - 1) {
            __threadfence();
            atomicAdd(gen, 1);
        } else {
            while (atomicAdd(gen, 0) == g) __builtin_amdgcn_s_sleep(4);
        }
        __threadfence();
    }
    __syncthreads();
}

// ---- fused: blocks [0,NB) = LDS histogram (+edge ranks); [NB,NB+2*GB) = dual GEMM ----
__global__ __launch_bounds__(256) void k_hist_gemm2(const int* __restrict__ dst,
                                                    int* __restrict__ hmat,
                                                    unsigned short* __restrict__ rank,
                                                    int* __restrict__ bar,
                                                    const float* __restrict__ X,
                                                    const float* __restrict__ W1,
                                                    const float* __restrict__ Wdown,
                                                    const float* __restrict__ bdown,
                                                    unsigned short* __restrict__ outT,
                                                    float* __restrict__ outB, int n) {
    __shared__ char smem[81920];     // union: hist 40KB | gemm xs 16KB + ws 64KB
    int t = threadIdx.x;

    if (blockIdx.x < NB) {
        // ---------------- histogram + rank branch ----------------
        int* hs = (int*)smem;
        if (blockIdx.x == 0 && t < 16) bar[t] = 0;   // zero barrier for k_mid
        for (int j = t; j < HP; j += 256) hs[j] = 0;
        __syncthreads();
        int base = blockIdx.x * CH;
#pragma unroll 4
        for (int j = t; j < CH; j += 256) {
            int r = atomicAdd(&hs[dst[base + j]], 1);
            rank[base + j] = (unsigned short)r;   // rank within (chunk, dst)
        }
        __syncthreads();
        int* out = hmat + blockIdx.x * HP;
        for (int j = t; j < N_NODES; j += 256) out[j] = hs[j];
        return;
    }

    // ---------------- GEMM branch ----------------
    float* xs = (float*)smem;                 // 32*128 f32
    float* wsm = (float*)(smem + 16384);      // 128*128 f32
    int bid = blockIdx.x - NB;
    int which = (bid >= GB) ? 1 : 0;
    int bx = which ? bid - GB : bid;
    int tile0 = bx * 32;
    const float* W = which ? Wdown : W1;

    const float4* Wv = (const float4*)W;
    float4* wsv = (float4*)wsm;
#pragma unroll
    for (int q = 0; q < 16; ++q) wsv[t + 256 * q] = Wv[t + 256 * q];

    const float4* Xv = (const float4*)X;
    float4* xsv = (float4*)xs;
#pragma unroll
    for (int q = 0; q < 4; ++q) {
        int idx = t + 256 * q;
        int row = tile0 + (idx >> 5);
        float4 v = make_float4(0.f, 0.f, 0.f, 0.f);
        if (row < n) v = Xv[(size_t)row * 32 + (idx & 31)];
        xsv[idx] = v;
    }
    __syncthreads();

    int c4 = t & 31;
    int rg = t >> 5;
    float4 acc[4];
#pragma unroll
    for (int p = 0; p < 4; ++p) acc[p] = make_float4(0.f, 0.f, 0.f, 0.f);

    const float4* wsr = (const float4*)wsm;
    const float4* xsr = (const float4*)xs;
#pragma unroll 4
    for (int kq = 0; kq < 32; ++kq) {
        float4 w0 = wsr[(4 * kq + 0) * 32 + c4];
        float4 w1 = wsr[(4 * kq + 1) * 32 + c4];
        float4 w2 = wsr[(4 * kq + 2) * 32 + c4];
        float4 w3 = wsr[(4 * kq + 3) * 32 + c4];
#pragma unroll
        for (int p = 0; p < 4; ++p) {
            float4 xv = xsr[(rg * 4 + p) * 32 + kq];
            acc[p].x += xv.x * w0.x + xv.y * w1.x + xv.z * w2.x + xv.w * w3.x;
            acc[p].y += xv.x * w0.y + xv.y * w1.y + xv.z * w2.y + xv.w * w3.y;
            acc[p].z += xv.x * w0.z + xv.y * w1.z + xv.z * w2.z + xv.w * w3.z;
            acc[p].w += xv.x * w0.w + xv.y * w1.w + xv.z * w2.w + xv.w * w3.w;
        }
    }
    if (which == 0) {
#pragma unroll
        for (int p = 0; p < 4; ++p) {
            int row = tile0 + rg * 4 + p;
            if (row < n) {
                ushort4_t o;
                o[0] = f2bf(acc[p].x); o[1] = f2bf(acc[p].y);
                o[2] = f2bf(acc[p].z); o[3] = f2bf(acc[p].w);
                ((ushort4_t*)outT)[(size_t)row * 32 + c4] = o;
            }
        }
    } else {
        float4 bv = ((const float4*)bdown)[c4];
#pragma unroll
        for (int p = 0; p < 4; ++p) {
            int row = tile0 + rg * 4 + p;
            if (row < n) {
                float4 o;
                o.x = acc[p].x + bv.x; o.y = acc[p].y + bv.y;
                o.z = acc[p].z + bv.z; o.w = acc[p].w + bv.w;
                ((float4*)outB)[(size_t)row * 32 + c4] = o;
            }
        }
    }
}

// ---- cooperative colsum + scan + base (40 blocks, 1 grid barrier) ----
__global__ __launch_bounds__(256) void k_mid(const int* __restrict__ h,
                                             int* bar,
                                             int* __restrict__ rangesum,
                                             int* __restrict__ offsets,
                                             float* __restrict__ dis,
                                             int* __restrict__ bmat) {
    __shared__ int sc[256];
    __shared__ int rsl[NBLK];
    __shared__ int sP;
    int b = blockIdx.x, t = threadIdx.x;
    int i = b * NPB2 + t;
    bool act = (t < NPB2);

    // phase 1: deg (column sum), dis, block range-sum
    int s = 0;
    if (act) {
#pragma unroll 5
        for (int bb = 0; bb < NB; ++bb) s += h[bb * HP + i];
        dis[i] = rsqrtf((float)(s + 1));   // +1 self-loop
    }
    sc[t] = s;
    __syncthreads();
#pragma unroll
    for (int off = 1; off < 256; off <<= 1) {
        int v = (t >= off) ? sc[t - off] : 0;
        __syncthreads();
        sc[t] += v;
        __syncthreads();
    }
    int lofs = sc[t] - s;
    if (t == 255) rangesum[b] = sc[255];
    gbar(bar, 0, NBLK);

    // phase 2: block prefix + offsets + per-(chunk,node) bases
    if (t < NBLK) rsl[t] = rangesum[t];
    __syncthreads();
    if (t == 0) {
        int P = 0;
        for (int bb = 0; bb < b; ++bb) P += rsl[bb];
        sP = P;
        if (b == NBLK - 1) offsets[N_NODES] = P + rsl[b];
    }
    __syncthreads();
    if (act) {
        int run = sP + lofs;
        offsets[i] = run;
#pragma unroll 5
        for (int bb = 0; bb < NB; ++bb) {
            bmat[bb * HP + i] = run;
            run += h[bb * HP + i];
        }
    }
}

// ---- edge-parallel scatter: pos = bmat[chunk][dst] + rank (no atomics) ----
__global__ __launch_bounds__(256) void k_scatter_ep(const int* __restrict__ src,
                                                    const int* __restrict__ dst,
                                                    const unsigned short* __restrict__ rank,
                                                    const int* __restrict__ bmat,
                                                    int* __restrict__ csr) {
    int e = blockIdx.x * 256 + threadIdx.x;          // grid covers E exactly
    int b = blockIdx.x / (CH / 256);                  // 25 blocks per chunk
    int d = dst[e];
    int s = src[e];
    int r = rank[e];
    int pos = bmat[b * HP + d] + r;
    csr[pos] = s;
}

// ---- single GEMM (T2 = h1 @ W2, bf16 out) ----
__global__ __launch_bounds__(256) void k_gemm(const float* __restrict__ X,
                                              const float* __restrict__ W,
                                              unsigned short* __restrict__ Y, int n) {
    __shared__ float xs[32 * 128];
    __shared__ float ws[128 * 128];
    int t = threadIdx.x;
    int tile0 = blockIdx.x * 32;

    const float4* Wv = (const float4*)W;
    float4* wsv = (float4*)ws;
#pragma unroll
    for (int q = 0; q < 16; ++q) wsv[t + 256 * q] = Wv[t + 256 * q];

    const float4* Xv = (const float4*)X;
    float4* xsv = (float4*)xs;
#pragma unroll
    for (int q = 0; q < 4; ++q) {
        int idx = t + 256 * q;
        int row = tile0 + (idx >> 5);
        float4 v = make_float4(0.f, 0.f, 0.f, 0.f);
        if (row < n) v = Xv[(size_t)row * 32 + (idx & 31)];
        xsv[idx] = v;
    }
    __syncthreads();

    int c4 = t & 31;
    int rg = t >> 5;
    float4 acc[4];
#pragma unroll
    for (int p = 0; p < 4; ++p) acc[p] = make_float4(0.f, 0.f, 0.f, 0.f);

    const float4* wsr = (const float4*)ws;
    const float4* xsr = (const float4*)xs;
#pragma unroll 4
    for (int kq = 0; kq < 32; ++kq) {
        float4 w0 = wsr[(4 * kq + 0) * 32 + c4];
        float4 w1 = wsr[(4 * kq + 1) * 32 + c4];
        float4 w2 = wsr[(4 * kq + 2) * 32 + c4];
        float4 w3 = wsr[(4 * kq + 3) * 32 + c4];
#pragma unroll
        for (int p = 0; p < 4; ++p) {
            float4 xv = xsr[(rg * 4 + p) * 32 + kq];
            acc[p].x += xv.x * w0.x + xv.y * w1.x + xv.z * w2.x + xv.w * w3.x;
            acc[p].y += xv.x * w0.y + xv.y * w1.y + xv.z * w2.y + xv.w * w3.y;
            acc[p].z += xv.x * w0.z + xv.y * w1.z + xv.z * w2.z + xv.w * w3.z;
            acc[p].w += xv.x * w0.w + xv.y * w1.w + xv.z * w2.w + xv.w * w3.w;
        }
    }
#pragma unroll
    for (int p = 0; p < 4; ++p) {
        int row = tile0 + rg * 4 + p;
        if (row < n) {
            ushort4_t o;
            o[0] = f2bf(acc[p].x); o[1] = f2bf(acc[p].y);
            o[2] = f2bf(acc[p].z); o[3] = f2bf(acc[p].w);
            ((ushort4_t*)Y)[(size_t)row * 32 + c4] = o;
        }
    }
}

// ---- layer-1 aggregation: h1 = relu(agg(T1)+b1) -> f32 ----
__global__ __launch_bounds__(256) void k_agg1(const unsigned short* __restrict__ T,
                                              const float* __restrict__ dis,
                                              const int* __restrict__ offsets,
                                              const int* __restrict__ csr,
                                              const float* __restrict__ bias,
                                              float* __restrict__ Y, int n) {
    __shared__ float red[3][16][9];
    int i = blockIdx.x;
    int t = threadIdx.x;
    int c8 = t & 15;
    int es = t >> 4;
    int wave = t >> 6;
    int lane = t & 63;

    int e0 = offsets[i], e1 = offsets[i + 1];
    const ushort8_t* T8 = (const ushort8_t*)T;

    float acc[8];
#pragma unroll
    for (int j = 0; j < 8; ++j) acc[j] = 0.f;

    int e = e0 + es;
    for (; e + 16 < e1; e += 32) {
        int s0 = csr[e];
        int s1 = csr[e + 16];
        float w0 = dis[s0];
        float w1 = dis[s1];
        ushort8_t v0 = T8[(size_t)s0 * 16 + c8];
        ushort8_t v1 = T8[(size_t)s1 * 16 + c8];
#pragma unroll
        for (int j = 0; j < 8; ++j)
            acc[j] += w0 * bf2f(v0[j]) + w1 * bf2f(v1[j]);
    }
    if (e < e1) {
        int s0 = csr[e];
        float w0 = dis[s0];
        ushort8_t v0 = T8[(size_t)s0 * 16 + c8];
#pragma unroll
        for (int j = 0; j < 8; ++j) acc[j] += w0 * bf2f(v0[j]);
    }

#pragma unroll
    for (int j = 0; j < 8; ++j) {
        acc[j] += __shfl_xor(acc[j], 16, 64);
        acc[j] += __shfl_xor(acc[j], 32, 64);
    }
    if (wave > 0 && lane < 16) {
#pragma unroll
        for (int j = 0; j < 8; ++j) red[wave - 1][lane][j] = acc[j];
    }
    __syncthreads();
    if (wave == 0 && lane < 16) {
#pragma unroll
        for (int j = 0; j < 8; ++j)
            acc[j] += red[0][lane][j] + red[1][lane][j] + red[2][lane][j];

        float di = dis[i];
        ushort8_t sv = T8[(size_t)i * 16 + c8];
#pragma unroll
        for (int j = 0; j < 8; ++j) acc[j] += di * bf2f(sv[j]);
#pragma unroll
        for (int j = 0; j < 8; ++j)
            acc[j] = fmaxf(di * acc[j] + bias[c8 * 8 + j], 0.f);

        float4* Y4 = (float4*)Y;
        Y4[(size_t)i * 32 + c8 * 2]     = make_float4(acc[0], acc[1], acc[2], acc[3]);
        Y4[(size_t)i * 32 + c8 * 2 + 1] = make_float4(acc[4], acc[5], acc[6], acc[7]);
    }
}

// ---- layer-2 aggregation fused with all three heads ----
__global__ __launch_bounds__(256) void k_agg2h(const unsigned short* __restrict__ T,
                                               const float* __restrict__ dis,
                                               const int* __restrict__ offsets,
                                               const int* __restrict__ csr,
                                               const float* __restrict__ bias,
                                               const float* __restrict__ resid,
                                               const float* __restrict__ Wlin,
                                               const float* __restrict__ blin,
                                               const float* __restrict__ Wd2,
                                               const float* __restrict__ bd2,
                                               const float* __restrict__ Wd3,
                                               const float* __restrict__ bd3,
                                               float* __restrict__ out1,
                                               float* __restrict__ out2,
                                               float* __restrict__ out3, int n) {
    __shared__ float red[3][16][9];
    __shared__ float hrow[128];
    int i = blockIdx.x;
    int t = threadIdx.x;
    int c8 = t & 15;
    int es = t >> 4;
    int wave = t >> 6;
    int lane = t & 63;

    int e0 = offsets[i], e1 = offsets[i + 1];
    const ushort8_t* T8 = (const ushort8_t*)T;

    float acc[8];
#pragma unroll
    for (int j = 0; j < 8; ++j) acc[j] = 0.f;

    int e = e0 + es;
    for (; e + 16 < e1; e += 32) {
        int s0 = csr[e];
        int s1 = csr[e + 16];
        float w0 = dis[s0];
        float w1 = dis[s1];
        ushort8_t v0 = T8[(size_t)s0 * 16 + c8];
        ushort8_t v1 = T8[(size_t)s1 * 16 + c8];
#pragma unroll
        for (int j = 0; j < 8; ++j)
            acc[j] += w0 * bf2f(v0[j]) + w1 * bf2f(v1[j]);
    }
    if (e < e1) {
        int s0 = csr[e];
        float w0 = dis[s0];
        ushort8_t v0 = T8[(size_t)s0 * 16 + c8];
#pragma unroll
        for (int j = 0; j < 8; ++j) acc[j] += w0 * bf2f(v0[j]);
    }

#pragma unroll
    for (int j = 0; j < 8; ++j) {
        acc[j] += __shfl_xor(acc[j], 16, 64);
        acc[j] += __shfl_xor(acc[j], 32, 64);
    }
    if (wave > 0 && lane < 16) {
#pragma unroll
        for (int j = 0; j < 8; ++j) red[wave - 1][lane][j] = acc[j];
    }
    __syncthreads();
    if (wave == 0 && lane < 16) {
#pragma unroll
        for (int j = 0; j < 8; ++j)
            acc[j] += red[0][lane][j] + red[1][lane][j] + red[2][lane][j];

        float di = dis[i];
        ushort8_t sv = T8[(size_t)i * 16 + c8];
#pragma unroll
        for (int j = 0; j < 8; ++j) acc[j] += di * bf2f(sv[j]);

        const float4* rv4 = (const float4*)resid;
        float4 r0 = rv4[(size_t)i * 32 + c8 * 2];
        float4 r1 = rv4[(size_t)i * 32 + c8 * 2 + 1];
#pragma unroll
        for (int j = 0; j < 8; ++j) acc[j] = di * acc[j] + bias[c8 * 8 + j];
        acc[0] += r0.x; acc[1] += r0.y; acc[2] += r0.z; acc[3] += r0.w;
        acc[4] += r1.x; acc[5] += r1.y; acc[6] += r1.z; acc[7] += r1.w;

#pragma unroll
        for (int j = 0; j < 8; ++j) hrow[c8 * 8 + j] = acc[j];
    }
    __syncthreads();

    if (wave == 0) {
        float h0 = hrow[lane];
        float h1 = hrow[64 + lane];
        float p2 = h0 * Wd2[lane] + h1 * Wd2[64 + lane];
        float p3 = h0 * Wd3[lane] + h1 * Wd3[64 + lane];
#pragma unroll
        for (int d = 1; d < 64; d <<= 1) {
            p2 += __shfl_xor(p2, d, 64);
            p3 += __shfl_xor(p3, d, 64);
        }
        if (lane == 0) {
            out2[i] = p2 + bd2[0];
            out3[i] = p3 + bd3[0];
        }
        int c = lane & 15, kg = lane >> 4;
        float z = 0.f;
#pragma unroll 8
        for (int j = 0; j < 32; ++j) {
            int k = kg * 32 + j;
            z += hrow[k] * Wlin[k * 16 + c];
        }
        z += __shfl_xor(z, 16, 64);
        z += __shfl_xor(z, 32, 64);
        z += blin[c];
        float m = z;
#pragma unroll
        for (int d = 1; d < 16; d <<= 1) m = fmaxf(m, __shfl_xor(m, d, 64));
        float ex = expf(z - m);
        float ssum = ex;
#pragma unroll
        for (int d = 1; d < 16; d <<= 1) ssum += __shfl_xor(ssum, d, 64);
        float lsm = z - m - logf(ssum);
        if (lane < 16) out1[(size_t)i * 16 + c] = lsm;
    }
}

extern "C" void kernel_launch(void* const* d_in, const int* in_sizes, int n_in,
                              void* d_out, int out_size, void* d_ws, size_t ws_size,
                              hipStream_t stream) {
    const float* x     = (const float*)d_in[0];
    const int*   ei    = (const int*)d_in[1];
    const float* W1    = (const float*)d_in[2];
    const float* b1    = (const float*)d_in[3];
    const float* W2    = (const float*)d_in[4];
    const float* b2    = (const float*)d_in[5];
    const float* Wlin1 = (const float*)d_in[6];
    const float* blin1 = (const float*)d_in[7];
    const float* Wdeg2 = (const float*)d_in[8];
    const float* bdeg2 = (const float*)d_in[9];
    const float* Wdeg3 = (const float*)d_in[10];
    const float* bdeg3 = (const float*)d_in[11];
    const float* Wdown = (const float*)d_in[12];
    const float* bdown = (const float*)d_in[13];

    const int n = N_NODES, E = N_EDGES;
    const int* src = ei;
    const int* dst = ei + E;

    char* ws = (char*)d_ws;
    int*            bar      = (int*)ws;                          // 64
    int*            hmat     = bar + 64;                          // NB*HP
    int*            bmat     = hmat + NB * HP;                    // NB*HP
    int*            rangesum = bmat + NB * HP;                    // 64
    int*            offsets  = rangesum + 64;                     // 10048
    float*          dis      = (float*)(offsets + 10048);         // 10016
    unsigned short* rank     = (unsigned short*)(dis + HP);       // E u16
    int*            csr      = (int*)(rank + E);                  // E
    unsigned short* bufT     = (unsigned short*)(csr + E);        // bf16 n*128
    float*          bufB     = (float*)(bufT + (size_t)n * 128);  // f32 n*128
    float*          bufC     = bufB + (size_t)n * 128;            // f32 n*128

    // 1: histogram+rank (100 blocks) || dual GEMM (626 blocks)
    k_hist_gemm2<<<NB + 2 * GB, 256, 0, stream>>>(dst, hmat, rank, bar, x, W1,
                                                  Wdown, bdown, bufT, bufB, n);
    // 2: colsum/scan/base (cooperative, 40 blocks)
    k_mid<<<NBLK, 256, 0, stream>>>(hmat, bar, rangesum, offsets, dis, bmat);
    // 3: edge-parallel scatter (2500 blocks, no atomics)
    k_scatter_ep<<<E / 256, 256, 0, stream>>>(src, dst, rank, bmat, csr);
    // 4: h1 = relu(agg(T1) + b1)
    k_agg1<<<n, 256, 0, stream>>>(bufT, dis, offsets, csr, b1, bufC, n);
    // 5: T2 = h1 @ W2
    k_gemm<<<(n + 31) / 32, 256, 0, stream>>>(bufC, W2, bufT, n);
    // 6: h2 = agg(T2) + b2 + orig, fused heads
    float* out1 = (float*)d_out;
    float* out2 = out1 + (size_t)n * 16;
    float* out3 = out2 + n;
    k_agg2h<<<n, 256, 0, stream>>>(bufT, dis, offsets, csr, b2, bufB,
                                   Wlin1, blin1, Wdeg2, bdeg2, Wdeg3, bdeg3,
                                   out1, out2, out3, n);
}